// Round 3
// baseline (286.965 us; speedup 1.0000x reference)
//
#include <hip/hip_runtime.h>

#define TX 128
#define TY 64
#define TILE_H 66            // TY + 2 halo rows
#define TILE_W 136           // quads cover [-4, 132) relative to tile x-origin
#define QROW 34              // float4 quads per staged row
#define NTX (1024 / TX)      // 8
#define NTY (1024 / TY)      // 16
#define NBATCH 16
#define NTILES (NTX * NTY * NBATCH)  // 2048
#define NBLOCKS 1024                 // 2 tiles per block
#define NHIST 8                      // global histogram copies

__global__ void lbp_zero_hist(unsigned* __restrict__ g_hist) {
    g_hist[blockIdx.x * 256 + threadIdx.x] = 0u;
}

__global__ __launch_bounds__(256) void lbp_hist_kernel(
        const float* __restrict__ img, unsigned* __restrict__ g_hist) {
    __shared__ __align__(16) float tile[TILE_H][TILE_W];   // 35904 B
    __shared__ unsigned s_hist[4][256];                    // 4096 B
    const int tid = threadIdx.x;
    const int wv  = tid >> 6;
    #pragma unroll
    for (int w = 0; w < 4; ++w) s_hist[w][tid] = 0u;

    const int g  = tid & 31;          // column group: pixels 4g..4g+3
    const int s  = tid >> 5;          // row slice: pixel rows 8s..8s+7
    const int cg = g << 2;
    const int r0 = s << 3;

    for (int t = blockIdx.x; t < NTILES; t += NBLOCKS) {
        const int bx  = t & (NTX - 1);
        const int rem = t >> 3;            // t / NTX
        const int by  = rem & (NTY - 1);
        const int b   = rem >> 4;          // rem / NTY
        const int y0  = by * TY - 1;       // global row of tile row 0
        const int xq0 = bx * TX - 4;       // global col of staged col 0 (16B aligned)
        const float* imgb = img + (size_t)b * 3u * 1024u * 1024u;

        __syncthreads();   // tile reused across grid-stride iterations

        // ---- stage gray tile: 66 rows x 34 aligned float4 quads ----
        for (int it = tid; it < TILE_H * QROW; it += 256) {
            const int row = it / QROW;
            const int q   = it - row * QROW;
            const int gy  = y0 + row;
            const int gxq = xq0 + (q << 2);
            float4 gv = make_float4(0.f, 0.f, 0.f, 0.f);
            if ((unsigned)gy < 1024u) {
                const float* rowp = imgb + (size_t)gy * 1024u;
                if ((unsigned)gxq <= 1020u) {   // fully in-bounds quad (common case)
                    const float4 r4 = *(const float4*)(rowp + gxq);
                    const float4 g4 = *(const float4*)(rowp + 1048576u + gxq);
                    const float4 b4 = *(const float4*)(rowp + 2097152u + gxq);
                    gv.x = (r4.x * 0.299f + g4.x * 0.587f) + b4.x * 0.114f;
                    gv.y = (r4.y * 0.299f + g4.y * 0.587f) + b4.y * 0.114f;
                    gv.z = (r4.z * 0.299f + g4.z * 0.587f) + b4.z * 0.114f;
                    gv.w = (r4.w * 0.299f + g4.w * 0.587f) + b4.w * 0.114f;
                } else {                         // edge quad: per-element masked
                    #pragma unroll
                    for (int k = 0; k < 4; ++k) {
                        const int gx = gxq + k;
                        if ((unsigned)gx < 1024u) {
                            const float r  = rowp[gx];
                            const float gc = rowp[1048576u + gx];
                            const float bb = rowp[2097152u + gx];
                            ((float*)&gv)[k] = (r * 0.299f + gc * 0.587f) + bb * 0.114f;
                        }
                    }
                }
            }
            *(float4*)&tile[row][q << 2] = gv;
        }
        __syncthreads();

        // ---- compute: 4 adjacent pixels x 8 rows per thread, rolling 3-row window ----
        // pixel col c (0..127) lives at LDS col c+4; window for pixels 4g..4g+3
        // spans LDS cols cg+3 .. cg+8: one aligned float4 at cg+4 + two edge floats.
        float  al = tile[r0    ][cg + 3];
        float4 am = *(const float4*)&tile[r0    ][cg + 4];
        float  ar = tile[r0    ][cg + 8];
        float  bl = tile[r0 + 1][cg + 3];
        float4 bm = *(const float4*)&tile[r0 + 1][cg + 4];
        float  br = tile[r0 + 1][cg + 8];
        #pragma unroll
        for (int p = 0; p < 8; ++p) {
            const int rb = r0 + p + 2;
            const float  cl2 = tile[rb][cg + 3];
            const float4 cm  = *(const float4*)&tile[rb][cg + 4];
            const float  cr2 = tile[rb][cg + 8];
            // bits: 0:(y-1,x+1) 1:(y,x+1) 2:(y+1,x+1) 3:(y+1,x)
            //       4:(y+1,x-1) 5:(y,x-1) 6:(y-1,x-1) 7:(y-1,x)
            const float c0 = bm.x;
            const unsigned code0 =
                (am.y >= c0 ? 1u:0u) | (bm.y >= c0 ? 2u:0u) | (cm.y >= c0 ? 4u:0u) |
                (cm.x >= c0 ? 8u:0u) | (cl2  >= c0 ? 16u:0u) | (bl  >= c0 ? 32u:0u) |
                (al   >= c0 ? 64u:0u) | (am.x >= c0 ? 128u:0u);
            const float c1 = bm.y;
            const unsigned code1 =
                (am.z >= c1 ? 1u:0u) | (bm.z >= c1 ? 2u:0u) | (cm.z >= c1 ? 4u:0u) |
                (cm.y >= c1 ? 8u:0u) | (cm.x >= c1 ? 16u:0u) | (bm.x >= c1 ? 32u:0u) |
                (am.x >= c1 ? 64u:0u) | (am.y >= c1 ? 128u:0u);
            const float c2 = bm.z;
            const unsigned code2 =
                (am.w >= c2 ? 1u:0u) | (bm.w >= c2 ? 2u:0u) | (cm.w >= c2 ? 4u:0u) |
                (cm.z >= c2 ? 8u:0u) | (cm.y >= c2 ? 16u:0u) | (bm.y >= c2 ? 32u:0u) |
                (am.y >= c2 ? 64u:0u) | (am.z >= c2 ? 128u:0u);
            const float c3 = bm.w;
            const unsigned code3 =
                (ar   >= c3 ? 1u:0u) | (br   >= c3 ? 2u:0u) | (cr2  >= c3 ? 4u:0u) |
                (cm.w >= c3 ? 8u:0u) | (cm.z >= c3 ? 16u:0u) | (bm.z >= c3 ? 32u:0u) |
                (am.z >= c3 ? 64u:0u) | (am.w >= c3 ? 128u:0u);
            atomicAdd(&s_hist[wv][code0], 1u);
            atomicAdd(&s_hist[wv][code1], 1u);
            atomicAdd(&s_hist[wv][code2], 1u);
            atomicAdd(&s_hist[wv][code3], 1u);
            al = bl; am = bm; ar = br;
            bl = cl2; bm = cm; br = cr2;
        }
    }

    __syncthreads();
    const unsigned total = s_hist[0][tid] + s_hist[1][tid] + s_hist[2][tid] + s_hist[3][tid];
    atomicAdd(&g_hist[((blockIdx.x & (NHIST - 1)) << 8) + tid], total);
}

__global__ __launch_bounds__(256) void lbp_finalize(
        const unsigned* __restrict__ g_hist, float* __restrict__ out) {
    __shared__ float red[256];
    const int i = threadIdx.x;
    unsigned hv = 0u;
    #pragma unroll
    for (int c = 0; c < NHIST; ++c) hv += g_hist[(c << 8) + i];
    const float h = (float)hv;
    red[i] = h;
    __syncthreads();
    #pragma unroll
    for (int s = 128; s > 0; s >>= 1) {
        if (i < s) red[i] += red[i + s];
        __syncthreads();
    }
    const float mean = red[0] * (1.0f / 256.0f);
    __syncthreads();
    const float d = h - mean;
    red[i] = d * d;
    __syncthreads();
    #pragma unroll
    for (int s = 128; s > 0; s >>= 1) {
        if (i < s) red[i] += red[i + s];
        __syncthreads();
    }
    const float stdv = sqrtf(red[0] * (1.0f / 255.0f));
    out[i] = d / stdv;
}

extern "C" void kernel_launch(void* const* d_in, const int* in_sizes, int n_in,
                              void* d_out, int out_size, void* d_ws, size_t ws_size,
                              hipStream_t stream) {
    const float* img = (const float*)d_in[0];
    unsigned* g_hist = (unsigned*)d_ws;   // NHIST * 256 * 4 bytes of scratch
    float* out = (float*)d_out;

    lbp_zero_hist<<<NHIST, 256, 0, stream>>>(g_hist);
    lbp_hist_kernel<<<NBLOCKS, 256, 0, stream>>>(img, g_hist);
    lbp_finalize<<<1, 256, 0, stream>>>(g_hist, out);
}